// Round 9
// baseline (222.104 us; speedup 1.0000x reference)
//
#include <hip/hip_runtime.h>
#include <hip/hip_bf16.h>

// B=8, N=256, D=128, E=32, H=4, HD=32
// ws layout (float/u32 offsets)
#define OFF_WQT 0          // 16384 transposed wq  [k][d]
#define OFF_WKT 16384
#define OFF_WVT 32768
#define OFF_OWT 49152      // transposed out_w [k][d]
#define OFF_GWT 65536      // transposed gcn_w [k][d]
#define OFF_WKE 81920      // 4096: wk@edge_w, row-major [d][e]
#define OFF_WVET 86016     // 4096: (wv@edge_w)^T, [e][d]
#define OFF_KB  90112      // 128 f32
#define OFF_VB  90240      // 128 f32
#define OFF_SC  90368      // 8192: per-row per-head score const
#define OFF_QSP 98560      // 131072 u32: q/sqrt(HD) packed f16 pairs (64/row)
#define OFF_QEP 229632     // 131072 u32: qe packed f16 pairs
#define OFF_HG  360704     // 262144 f32: gcn branch output (incl gcn_b)
#define OFF_EB  622848     // 262144 f32: normalized ebar per row
#define OFF_OV  884992     // 262144 f32: normalized attn@V0 per row
#define OFF_K0P 1147136    // 131072 u32: K0 packed f16 (64/row)
#define OFF_V0P 1278208    // 131072 u32: V0 packed f16 (kept for layout stability)
#define OFF_V0F 1409280    // 262144 f32: V0 full-precision (P3 fast path)
// total 1671424 floats = 6.69 MB (ws is ~268 MB)

// gfx950 builtins use the __fp16 ext-vector type (NOT _Float16)
using half2_t = __attribute__((ext_vector_type(2))) __fp16;

static __device__ __forceinline__ half2_t u2h(unsigned int u){
  union { unsigned int u; half2_t h; } x; x.u = u; return x.h;
}
static __device__ __forceinline__ unsigned int pkf16(float a, float b){
  union { half2_t h; unsigned int u; } x;
  x.h = __builtin_amdgcn_cvt_pkrtz(a, b);
  return x.u;
}
static __device__ __forceinline__ float fdot2(unsigned int a, unsigned int b, float c){
  return __builtin_amdgcn_fdot2(u2h(a), u2h(b), c, false);
}

// ---------------------------------------------------------------------------
// Kernel A (prep): 5 weight transposes + Wke / WveT + fused biases.
// ---------------------------------------------------------------------------
__global__ __launch_bounds__(256) void prep_kernel(
    const float* __restrict__ wq, const float* __restrict__ wk,
    const float* __restrict__ wv, const float* __restrict__ out_w,
    const float* __restrict__ gcn_w, const float* __restrict__ edge_w,
    const float* __restrict__ edge_b, const float* __restrict__ bk,
    const float* __restrict__ bv, float* __restrict__ ws)
{
  int blk = blockIdx.x, t = threadIdx.x;
  if (blk < 320) {
    int w = blk >> 6;
    int e0 = (blk & 63) * 256 + t;
    const float* src = (w==0) ? wq : (w==1) ? wk : (w==2) ? wv : (w==3) ? out_w : gcn_w;
    float* dst = ws + ((w==0) ? OFF_WQT : (w==1) ? OFF_WKT : (w==2) ? OFF_WVT
                      : (w==3) ? OFF_OWT : OFF_GWT);
    int k = e0 >> 7, d = e0 & 127;
    dst[e0] = src[d*128 + k];
  } else if (blk < 352) {
    int idx = blk - 320;
    int which = idx >> 4;                  // 0: Wke (row-major), 1: WveT (transposed)
    int e0 = (idx & 15) * 256 + t;
    int dd = e0 >> 5, e = e0 & 31;
    const float* W = which ? wv : wk;
    float acc = 0.f;
    #pragma unroll 4
    for (int k2 = 0; k2 < 128; ++k2) acc += W[dd*128+k2] * edge_w[k2*32+e];
    if (which) ws[OFF_WVET + e*128 + dd] = acc;
    else       ws[OFF_WKE + e0] = acc;
  } else {
    int dd = t & 127;
    const float* W  = (t < 128) ? wk : wv;
    const float* bb = (t < 128) ? bk : bv;
    float acc = bb[dd];
    #pragma unroll 4
    for (int k2 = 0; k2 < 128; ++k2) acc += W[dd*128+k2] * edge_b[k2];
    ws[((t < 128) ? OFF_KB : OFF_VB) + dd] = acc;
  }
}

// ---------------------------------------------------------------------------
// Kernel B (proj): packed-f16 qs/qe/K0 + f32 V0F, f32 sc, GCN branch (HG).
// 2 rows/block, grid 1024. Transposed weights -> coalesced.
// ---------------------------------------------------------------------------
__global__ __launch_bounds__(256) void proj_kernel(
    const float* __restrict__ h, const float* __restrict__ adj,
    const float* __restrict__ bq, const float* __restrict__ gcn_b,
    float* __restrict__ ws)
{
  __shared__ float h_lds[256];        // 2 x 128
  __shared__ float adj_lds[512];      // 2 x 256
  __shared__ float p1[2][2][128];
  __shared__ float p2[2][2][128];
  __shared__ float p3[2][2][128];
  __shared__ float qrow[2*132];
  __shared__ float qe_l[2*132];
  __shared__ float dpart[2][2];
  __shared__ float ha_lds[2*132];

  int t = threadIdx.x;
  int d = t & 127, kh = t >> 7;
  int r0 = blockIdx.x * 2;
  int b  = r0 >> 8, n0 = r0 & 255;
  unsigned int* wsu = (unsigned int*)ws;

  if (t < 64)  ((float4*)h_lds)[t]   = ((const float4*)(h   + (size_t)r0*128))[t];
  if (t < 128) ((float4*)adj_lds)[t] = ((const float4*)(adj + (size_t)r0*256))[t];
  __syncthreads();

  // --- A: qkv matvecs, transposed weights (lane-d coalesced) ---
  {
    const float* wqT = ws + OFF_WQT;
    const float* wkT = ws + OFF_WKT;
    const float* wvT = ws + OFF_WVT;
    float aq0=0,aq1=0,ak0=0,ak1=0,av0=0,av1=0;
    #pragma unroll 4
    for (int kk = 0; kk < 64; ++kk) {
      int k = kh*64 + kk;
      float qw = wqT[k*128+d], kw = wkT[k*128+d], vw = wvT[k*128+d];
      float h0 = h_lds[k], h1 = h_lds[128+k];
      aq0 += qw*h0; aq1 += qw*h1;
      ak0 += kw*h0; ak1 += kw*h1;
      av0 += vw*h0; av1 += vw*h1;
    }
    p1[kh][0][d]=aq0; p1[kh][1][d]=aq1;
    p2[kh][0][d]=ak0; p2[kh][1][d]=ak1;
    p3[kh][0][d]=av0; p3[kh][1][d]=av1;
  }
  __syncthreads();

  // --- B: qrow (f32 LDS) + K pack + V f32 to global ---
  {
    int i = t >> 7, dd = t & 127;
    const float inv = 0.17677669529663687f;   // 1/sqrt(32)
    qrow[i*132 + dd] = (p1[0][i][dd] + p1[1][i][dd] + bq[dd]) * inv;
  }
  {
    int i = (t >> 6) & 1, pr = t & 63;
    if (t < 128) {
      float k0 = p2[0][i][2*pr] + p2[1][i][2*pr];
      float k1 = p2[0][i][2*pr+1] + p2[1][i][2*pr+1];
      wsu[OFF_K0P + (size_t)(r0+i)*64 + pr] = pkf16(k0, k1);
    } else {
      float v0 = p3[0][i][2*pr] + p3[1][i][2*pr];
      float v1 = p3[0][i][2*pr+1] + p3[1][i][2*pr+1];
      float2 vf; vf.x = v0; vf.y = v1;
      *(float2*)(ws + OFF_V0F + (size_t)(r0+i)*128 + 2*pr) = vf;
    }
  }
  __syncthreads();   // qrow ready; p1..p3 free

  // --- C: qs-pack, qe compute, sc, GCN aggregation ---
  if (t < 128) {
    int i = t >> 6, pr = t & 63;
    wsu[OFF_QSP + (size_t)(r0+i)*64 + pr] = pkf16(qrow[i*132 + 2*pr], qrow[i*132 + 2*pr+1]);
  }
  {
    int i = t >> 7, he = t & 127, hh = he >> 5, e = he & 31;
    float acc = 0.f;
    #pragma unroll
    for (int j = 0; j < 32; ++j)
      acc += ws[OFF_WKE + (hh*32 + j)*32 + e] * qrow[i*132 + hh*32 + j];
    qe_l[i*132 + he] = acc;
  }
  if (t < 8) {
    int i = t >> 2, hh = t & 3;
    float acc = 0.f;
    #pragma unroll
    for (int j = 0; j < 32; ++j)
      acc += qrow[i*132 + hh*32 + j] * ws[OFF_KB + hh*32 + j];
    ws[OFF_SC + (size_t)(r0+i)*4 + hh] = acc;
  }
  {
    float ag0=0, ag1=0, dg0=0, dg1=0;
    #pragma unroll 4
    for (int mm = 0; mm < 128; ++mm) {
      int ml = kh*128 + mm;
      float hv = h[((size_t)b*256 + ml)*128 + d];
      float a0 = adj_lds[ml]       + ((ml == n0)     ? 1.0f : 0.0f);
      float a1 = adj_lds[256 + ml] + ((ml == n0 + 1) ? 1.0f : 0.0f);
      ag0 += a0*hv; ag1 += a1*hv; dg0 += a0; dg1 += a1;
    }
    p1[kh][0][d]=ag0; p1[kh][1][d]=ag1;
    if (d == 0) { dpart[kh][0]=dg0; dpart[kh][1]=dg1; }
  }
  __syncthreads();

  // --- D: qe-pack + ha ---
  if (t < 128) {
    int i = t >> 6, pr = t & 63;
    wsu[OFF_QEP + (size_t)(r0+i)*64 + pr] = pkf16(qe_l[i*132 + 2*pr], qe_l[i*132 + 2*pr+1]);
  }
  {
    int i = t >> 7, dd = t & 127;
    ha_lds[i*132 + dd] = (p1[0][i][dd] + p1[1][i][dd]) / (dpart[0][i] + dpart[1][i]);
  }
  __syncthreads();

  // --- E: gcn matvec (transposed, coalesced) ---
  {
    const float* gwT = ws + OFF_GWT;
    float g0=0, g1=0;
    #pragma unroll 4
    for (int kk = 0; kk < 64; ++kk) {
      int k = kh*64 + kk;
      float gw = gwT[k*128+d];
      g0 += gw * ha_lds[k];
      g1 += gw * ha_lds[132 + k];
    }
    p2[kh][0][d]=g0; p2[kh][1][d]=g1;
  }
  __syncthreads();
  {
    int i = t >> 7, dd = t & 127;
    ws[OFF_HG + (size_t)(r0+i)*128 + dd] = p2[0][i][dd] + p2[1][i][dd] + gcn_b[dd];
  }
}

// ---------------------------------------------------------------------------
// Kernel C (attn): f16 dot2 scores; P3 with vector a-loads (stride-260
// s_lds, ds_read_b128) + f32 float4 V loads. LDS ~26.5 KB -> 6 blocks/CU.
// ---------------------------------------------------------------------------
__global__ __launch_bounds__(256, 6) void attn_kernel(
    const float* __restrict__ edge, const float* __restrict__ adj,
    const float* __restrict__ srcm, const float* __restrict__ ws,
    float* __restrict__ dummy)
{
  __shared__ unsigned int e_lds[256*18];       // f16 edge rows: 16 data + mask + hole
  __shared__ __align__(16) float s_lds[4*260]; // unnorm exp, stride 260 (16B-aligned)
  __shared__ float parts[2][512];              // 4 groups x 128 cols (ebar / ov)
  __shared__ unsigned int qe_lds[64];          // qe packed (4 heads x 16)
  __shared__ float wpart[16];

  const int t  = threadIdx.x;
  const int bn = blockIdx.x;
  const int b  = bn >> 8;
  const int hh = t & 3;
  const int mq = t >> 2;
  const unsigned int* wsu = (const unsigned int*)ws;

  // ---- P1: coalesced edge tile -> f16 LDS; mask -> slot 16; qe -> LDS ----
  {
    const float4* et = (const float4*)(edge + (size_t)bn*8192);
    #pragma unroll
    for (int it = 0; it < 8; ++it) {
      int fi = it*256 + t;
      float4 v = et[fi];
      int row = fi >> 3, c4 = fi & 7;
      uint2 pk;
      pk.x = pkf16(v.x, v.y);
      pk.y = pkf16(v.z, v.w);
      *(uint2*)(e_lds + row*18 + c4*2) = pk;
    }
    float mp = adj[(size_t)bn*256 + t] * srcm[(size_t)bn*256 + t];
    e_lds[t*18 + 16] = __float_as_uint(mp);
    if (t < 64) qe_lds[t] = wsu[OFF_QEP + (size_t)bn*64 + t];
  }
  // per-lane q packed registers for its head
  unsigned int qs_pk[16];
  {
    const uint4* qp = (const uint4*)(wsu + OFF_QSP + (size_t)bn*64 + hh*16);
    #pragma unroll
    for (int j = 0; j < 4; ++j) {
      uint4 a = qp[j];
      qs_pk[4*j+0]=a.x; qs_pk[4*j+1]=a.y; qs_pk[4*j+2]=a.z; qs_pk[4*j+3]=a.w;
    }
  }
  float sconst = ws[OFF_SC + (size_t)bn*4 + hh];
  __syncthreads();

  // ---- P2: scores, 4 passes; unnormalized exp into s_lds ----
  float exacc = 0.f;
  {
    const unsigned int* K0 = wsu + OFF_K0P + (size_t)b*16384;
    for (int pass = 0; pass < 4; ++pass) {
      int mm = (pass << 6) | mq;
      float acc = sconst;
      const uint4* kr4 = (const uint4*)(K0 + (size_t)mm*64 + hh*16);
      #pragma unroll
      for (int j4 = 0; j4 < 4; ++j4) {
        uint4 kw = kr4[j4];
        acc = fdot2(qs_pk[4*j4+0], kw.x, acc);
        acc = fdot2(qs_pk[4*j4+1], kw.y, acc);
        acc = fdot2(qs_pk[4*j4+2], kw.z, acc);
        acc = fdot2(qs_pk[4*j4+3], kw.w, acc);
      }
      const uint2* er = (const uint2*)(e_lds + mm*18);
      #pragma unroll
      for (int j2 = 0; j2 < 8; ++j2) {
        uint2 w = er[j2];
        acc = fdot2(qe_lds[hh*16 + 2*j2],     w.x, acc);
        acc = fdot2(qe_lds[hh*16 + 2*j2 + 1], w.y, acc);
      }
      float mp = __uint_as_float(e_lds[mm*18 + 16]);
      float ex = (mp == 0.0f) ? 0.0f : __expf(acc);   // no max-sub: |s| << 88
      s_lds[hh*260 + mm] = ex;
      exacc += ex;
    }
    // reduce exp-sums across lanes with same head
    exacc += __shfl_down(exacc, 4);
    exacc += __shfl_down(exacc, 8);
    exacc += __shfl_down(exacc, 16);
    exacc += __shfl_down(exacc, 32);
    if ((t & 63) < 4) wpart[(t >> 6)*4 + hh] = exacc;
  }
  __syncthreads();

  // ---- P3: ebar / ov partials, vectorized a-loads + f32 V ----
  {
    int ms  = t >> 5;
    int hh4 = (t >> 3) & 3, e4 = t & 7;
    int c   = t & 31,  hh5 = c >> 3;
    float p4x=0,p4y=0,p4z=0,p4w=0;
    float p5x=0,p5y=0,p5z=0,p5w=0;
    const float* vbase = ws + OFF_V0F + (size_t)b*32768;
    #pragma unroll
    for (int jg = 0; jg < 8; ++jg) {
      int m0 = ms*32 + jg*4;
      float4 a4v = *(const float4*)(s_lds + hh4*260 + m0);
      float4 a5v = *(const float4*)(s_lds + hh5*260 + m0);
      // e part (f16 LDS)
      {
        uint2 w0 = *(const uint2*)(e_lds + (m0+0)*18 + e4*2);
        uint2 w1 = *(const uint2*)(e_lds + (m0+1)*18 + e4*2);
        uint2 w2 = *(const uint2*)(e_lds + (m0+2)*18 + e4*2);
        uint2 w3 = *(const uint2*)(e_lds + (m0+3)*18 + e4*2);
        half2_t a0=u2h(w0.x), b0=u2h(w0.y);
        half2_t a1=u2h(w1.x), b1=u2h(w1.y);
        half2_t a2=u2h(w2.x), b2=u2h(w2.y);
        half2_t a3=u2h(w3.x), b3=u2h(w3.y);
        p4x += a4v.x*(float)a0.x + a4v.y*(float)a1.x + a4v.z*(float)a2.x + a4v.w*(float)a3.x;
        p4y += a4v.x*(float)a0.y + a4v.y*(float)a1.y + a4v.z*(float)a2.y + a4v.w*(float)a3.y;
        p4z += a4v.x*(float)b0.x + a4v.y*(float)b1.x + a4v.z*(float)b2.x + a4v.w*(float)b3.x;
        p4w += a4v.x*(float)b0.y + a4v.y*(float)b1.y + a4v.z*(float)b2.y + a4v.w*(float)b3.y;
      }
      // V part (f32 global, coalesced float4)
      {
        float4 v0 = *(const float4*)(vbase + (size_t)(m0+0)*128 + c*4);
        float4 v1 = *(const float4*)(vbase + (size_t)(m0+1)*128 + c*4);
        float4 v2 = *(const float4*)(vbase + (size_t)(m0+2)*128 + c*4);
        float4 v3 = *(const float4*)(vbase + (size_t)(m0+3)*128 + c*4);
        p5x += a5v.x*v0.x + a5v.y*v1.x + a5v.z*v2.x + a5v.w*v3.x;
        p5y += a5v.x*v0.y + a5v.y*v1.y + a5v.z*v2.y + a5v.w*v3.y;
        p5z += a5v.x*v0.z + a5v.y*v1.z + a5v.z*v2.z + a5v.w*v3.z;
        p5w += a5v.x*v0.w + a5v.y*v1.w + a5v.z*v2.w + a5v.w*v3.w;
      }
    }
    // combine ms pairs (2w, 2w+1) within each wave
    p4x += __shfl_xor(p4x, 32); p4y += __shfl_xor(p4y, 32);
    p4z += __shfl_xor(p4z, 32); p4w += __shfl_xor(p4w, 32);
    p5x += __shfl_xor(p5x, 32); p5y += __shfl_xor(p5y, 32);
    p5z += __shfl_xor(p5z, 32); p5w += __shfl_xor(p5w, 32);
    if ((t & 32) == 0) {
      int g = t >> 6;   // wave id = partial group
      float4 f4; f4.x=p4x; f4.y=p4y; f4.z=p4z; f4.w=p4w;
      *(float4*)(&parts[0][g*128 + hh4*32 + e4*4]) = f4;
      float4 f5; f5.x=p5x; f5.y=p5y; f5.z=p5z; f5.w=p5w;
      *(float4*)(&parts[1][g*128 + c*4]) = f5;
    }
  }
  __syncthreads();

  // ---- P4: reduce 4 groups, normalize, write ebar/ov ----
  if (t < 128) {
    int ht = t >> 5;
    float inv = 1.0f / (wpart[ht] + wpart[4+ht] + wpart[8+ht] + wpart[12+ht]);
    float se = 0.f, s2 = 0.f;
    #pragma unroll
    for (int g = 0; g < 4; ++g) { se += parts[0][g*128 + t]; s2 += parts[1][g*128 + t]; }
    float* wso = (float*)ws;
    wso[OFF_EB + (size_t)bn*128 + t] = se * inv;
    wso[OFF_OV + (size_t)bn*128 + t] = s2 * inv;
  }
  (void)dummy;
}

// ---------------------------------------------------------------------------
// Kernel D (epi): o = ov + WveT@ebar + vb; x = h + o@out_w^T + out_b;
// LN(x) + HG -> out. 4 rows/block, grid 512.
// ---------------------------------------------------------------------------
__global__ __launch_bounds__(256) void epi_kernel(
    const float* __restrict__ h, const float* __restrict__ out_b,
    const float* __restrict__ ln_g, const float* __restrict__ ln_b,
    const float* __restrict__ ws, float* __restrict__ out)
{
  __shared__ float eb_l[4*132];
  __shared__ float o_l[4*132];
  __shared__ float xl[4*132];
  __shared__ float pp[2][4][128];
  __shared__ float stat[8];

  int t = threadIdx.x;
  int d = t & 127, kh = t >> 7;
  int r0 = blockIdx.x * 4;

  #pragma unroll
  for (int rep = 0; rep < 2; ++rep) {
    int idx = rep*256 + t, i = idx >> 7, dd = idx & 127;
    eb_l[i*132 + dd] = ws[OFF_EB + (size_t)(r0+i)*128 + dd];
  }
  __syncthreads();

  #pragma unroll
  for (int rep = 0; rep < 2; ++rep) {
    int idx = rep*256 + t, i = idx >> 7, dd = idx & 127;
    int hd = dd >> 5;
    float acc = ws[OFF_OV + (size_t)(r0+i)*128 + dd] + ws[OFF_VB + dd];
    const float* wveT = ws + OFF_WVET;
    #pragma unroll 4
    for (int e = 0; e < 32; ++e) acc += wveT[e*128 + dd] * eb_l[i*132 + hd*32 + e];
    o_l[i*132 + dd] = acc;
  }
  __syncthreads();

  {
    const float* owT = ws + OFF_OWT;
    float xa[4] = {0,0,0,0};
    #pragma unroll 4
    for (int kk = 0; kk < 64; ++kk) {
      int k = kh*64 + kk;
      float ow = owT[k*128 + d];
      #pragma unroll
      for (int i = 0; i < 4; ++i) xa[i] += ow * o_l[i*132 + k];
    }
    #pragma unroll
    for (int i = 0; i < 4; ++i) pp[kh][i][d] = xa[i];
  }
  __syncthreads();

  #pragma unroll
  for (int rep = 0; rep < 2; ++rep) {
    int idx = rep*256 + t, i = idx >> 7, dd = idx & 127;
    xl[i*132 + dd] = pp[0][i][dd] + pp[1][i][dd] + out_b[dd]
                   + h[(size_t)(r0+i)*128 + dd];
  }
  __syncthreads();

  {
    int i = t >> 6, l = t & 63;
    float x0 = xl[i*132 + l], x1 = xl[i*132 + l + 64];
    float s = x0 + x1, ss = x0*x0 + x1*x1;
    #pragma unroll
    for (int off = 32; off > 0; off >>= 1) {
      s  += __shfl_down(s,  off);
      ss += __shfl_down(ss, off);
    }
    if (l == 0) {
      float mu  = s * (1.0f/128.0f);
      float var = ss * (1.0f/128.0f) - mu*mu;
      stat[i]   = mu;
      stat[4+i] = rsqrtf(var + 1e-5f);
    }
  }
  __syncthreads();

  #pragma unroll
  for (int rep = 0; rep < 2; ++rep) {
    int idx = rep*256 + t, i = idx >> 7, dd = idx & 127;
    float x = xl[i*132 + dd];
    out[(size_t)(r0+i)*128 + dd] =
        ln_g[dd]*(x - stat[i])*stat[4+i] + ln_b[dd] + ws[OFF_HG + (size_t)(r0+i)*128 + dd];
  }
}

// ---------------------------------------------------------------------------
extern "C" void kernel_launch(void* const* d_in, const int* in_sizes, int n_in,
                              void* d_out, int out_size, void* d_ws, size_t ws_size,
                              hipStream_t stream) {
  (void)in_sizes; (void)n_in; (void)out_size; (void)ws_size;
  const float* h     = (const float*)d_in[0];
  const float* adj   = (const float*)d_in[1];
  const float* edge  = (const float*)d_in[2];
  const float* srcm  = (const float*)d_in[3];
  const float* gcn_w = (const float*)d_in[4];
  const float* gcn_b = (const float*)d_in[5];
  const float* edge_w= (const float*)d_in[6];
  const float* edge_b= (const float*)d_in[7];
  const float* wq    = (const float*)d_in[8];
  const float* wk    = (const float*)d_in[9];
  const float* wv    = (const float*)d_in[10];
  const float* bq    = (const float*)d_in[11];
  const float* bk    = (const float*)d_in[12];
  const float* bv    = (const float*)d_in[13];
  const float* out_w = (const float*)d_in[14];
  const float* out_b = (const float*)d_in[15];
  const float* ln_g  = (const float*)d_in[16];
  const float* ln_b  = (const float*)d_in[17];

  float* ws  = (float*)d_ws;   // needs >= 6.69 MB
  float* out = (float*)d_out;

  prep_kernel<<<353, 256, 0, stream>>>(wq, wk, wv, out_w, gcn_w, edge_w, edge_b, bk, bv, ws);
  proj_kernel<<<1024, 256, 0, stream>>>(h, adj, bq, gcn_b, ws);
  attn_kernel<<<2048, 256, 0, stream>>>(edge, adj, srcm, ws, out);
  epi_kernel<<<512, 256, 0, stream>>>(h, out_b, ln_g, ln_b, ws, out);
}

// Round 10
// 188.338 us; speedup vs baseline: 1.1793x; 1.1793x over previous
//
#include <hip/hip_runtime.h>
#include <hip/hip_bf16.h>

// B=8, N=256, D=128, E=32, H=4, HD=32
// ws layout (float/u32 offsets)
#define OFF_WQT 0          // 16384 transposed wq  [k][d]
#define OFF_WKT 16384
#define OFF_WVT 32768
#define OFF_OWT 49152      // transposed out_w [k][d]
#define OFF_GWT 65536      // transposed gcn_w [k][d]
#define OFF_WKE 81920      // 4096: wk@edge_w, row-major [d][e]
#define OFF_WVET 86016     // 4096: (wv@edge_w)^T, [e][d]
#define OFF_KB  90112      // 128 f32
#define OFF_VB  90240      // 128 f32
#define OFF_SC  90368      // 8192: per-row per-head score const
#define OFF_QSP 98560      // 131072 u32: q/sqrt(HD) packed f16 pairs (64/row)
#define OFF_QEP 229632     // 131072 u32: qe packed f16 pairs
#define OFF_HG  360704     // 262144 f32: gcn branch output (incl gcn_b)
#define OFF_EB  622848     // 262144 f32: normalized ebar per row (4h x 32e)
#define OFF_OV  884992     // 262144 f32: normalized attn@V0 per row
#define OFF_K0P 1147136    // 131072 u32: K0 packed f16 (64/row)
#define OFF_V0P 1278208    // 131072 u32: V0 packed f16
// total 1409280 floats = 5.64 MB

// gfx950 builtins use the __fp16 ext-vector type (NOT _Float16)
using half2_t = __attribute__((ext_vector_type(2))) __fp16;

static __device__ __forceinline__ half2_t u2h(unsigned int u){
  union { unsigned int u; half2_t h; } x; x.u = u; return x.h;
}
static __device__ __forceinline__ unsigned int pkf16(float a, float b){
  union { half2_t h; unsigned int u; } x;
  x.h = __builtin_amdgcn_cvt_pkrtz(a, b);
  return x.u;
}
static __device__ __forceinline__ float fdot2(unsigned int a, unsigned int b, float c){
  return __builtin_amdgcn_fdot2(u2h(a), u2h(b), c, false);
}

// ---------------------------------------------------------------------------
// Kernel A (prep): 5 weight transposes + Wke / WveT + fused biases.
// ---------------------------------------------------------------------------
__global__ __launch_bounds__(256) void prep_kernel(
    const float* __restrict__ wq, const float* __restrict__ wk,
    const float* __restrict__ wv, const float* __restrict__ out_w,
    const float* __restrict__ gcn_w, const float* __restrict__ edge_w,
    const float* __restrict__ edge_b, const float* __restrict__ bk,
    const float* __restrict__ bv, float* __restrict__ ws)
{
  int blk = blockIdx.x, t = threadIdx.x;
  if (blk < 320) {
    int w = blk >> 6;
    int e0 = (blk & 63) * 256 + t;
    const float* src = (w==0) ? wq : (w==1) ? wk : (w==2) ? wv : (w==3) ? out_w : gcn_w;
    float* dst = ws + ((w==0) ? OFF_WQT : (w==1) ? OFF_WKT : (w==2) ? OFF_WVT
                      : (w==3) ? OFF_OWT : OFF_GWT);
    int k = e0 >> 7, d = e0 & 127;
    dst[e0] = src[d*128 + k];
  } else if (blk < 352) {
    int idx = blk - 320;
    int which = idx >> 4;                  // 0: Wke (row-major), 1: WveT (transposed)
    int e0 = (idx & 15) * 256 + t;
    int dd = e0 >> 5, e = e0 & 31;
    const float* W = which ? wv : wk;
    float acc = 0.f;
    #pragma unroll 4
    for (int k2 = 0; k2 < 128; ++k2) acc += W[dd*128+k2] * edge_w[k2*32+e];
    if (which) ws[OFF_WVET + e*128 + dd] = acc;
    else       ws[OFF_WKE + e0] = acc;
  } else {
    int dd = t & 127;
    const float* W  = (t < 128) ? wk : wv;
    const float* bb = (t < 128) ? bk : bv;
    float acc = bb[dd];
    #pragma unroll 4
    for (int k2 = 0; k2 < 128; ++k2) acc += W[dd*128+k2] * edge_b[k2];
    ws[((t < 128) ? OFF_KB : OFF_VB) + dd] = acc;
  }
}

// ---------------------------------------------------------------------------
// Kernel B (proj): packed-f16 qs/qe/K0/V0, f32 sc, GCN branch (HG).
// 2 rows/block, grid 1024. Transposed weights -> coalesced.
// ---------------------------------------------------------------------------
__global__ __launch_bounds__(256) void proj_kernel(
    const float* __restrict__ h, const float* __restrict__ adj,
    const float* __restrict__ bq, const float* __restrict__ gcn_b,
    float* __restrict__ ws)
{
  __shared__ float h_lds[256];        // 2 x 128
  __shared__ float adj_lds[512];      // 2 x 256
  __shared__ float p1[2][2][128];
  __shared__ float p2[2][2][128];
  __shared__ float p3[2][2][128];
  __shared__ float qrow[2*132];
  __shared__ float qe_l[2*132];
  __shared__ float dpart[2][2];
  __shared__ float ha_lds[2*132];

  int t = threadIdx.x;
  int d = t & 127, kh = t >> 7;
  int r0 = blockIdx.x * 2;
  int b  = r0 >> 8, n0 = r0 & 255;
  unsigned int* wsu = (unsigned int*)ws;

  if (t < 64)  ((float4*)h_lds)[t]   = ((const float4*)(h   + (size_t)r0*128))[t];
  if (t < 128) ((float4*)adj_lds)[t] = ((const float4*)(adj + (size_t)r0*256))[t];
  __syncthreads();

  // --- A: qkv matvecs, transposed weights (lane-d coalesced) ---
  {
    const float* wqT = ws + OFF_WQT;
    const float* wkT = ws + OFF_WKT;
    const float* wvT = ws + OFF_WVT;
    float aq0=0,aq1=0,ak0=0,ak1=0,av0=0,av1=0;
    #pragma unroll 4
    for (int kk = 0; kk < 64; ++kk) {
      int k = kh*64 + kk;
      float qw = wqT[k*128+d], kw = wkT[k*128+d], vw = wvT[k*128+d];
      float h0 = h_lds[k], h1 = h_lds[128+k];
      aq0 += qw*h0; aq1 += qw*h1;
      ak0 += kw*h0; ak1 += kw*h1;
      av0 += vw*h0; av1 += vw*h1;
    }
    p1[kh][0][d]=aq0; p1[kh][1][d]=aq1;
    p2[kh][0][d]=ak0; p2[kh][1][d]=ak1;
    p3[kh][0][d]=av0; p3[kh][1][d]=av1;
  }
  __syncthreads();

  // --- B: qrow (f32 LDS) + K/V pack to global ---
  {
    int i = t >> 7, dd = t & 127;
    const float inv = 0.17677669529663687f;   // 1/sqrt(32)
    qrow[i*132 + dd] = (p1[0][i][dd] + p1[1][i][dd] + bq[dd]) * inv;
  }
  {
    int i = (t >> 6) & 1, pr = t & 63;
    if (t < 128) {
      float k0 = p2[0][i][2*pr] + p2[1][i][2*pr];
      float k1 = p2[0][i][2*pr+1] + p2[1][i][2*pr+1];
      wsu[OFF_K0P + (size_t)(r0+i)*64 + pr] = pkf16(k0, k1);
    } else {
      float v0 = p3[0][i][2*pr] + p3[1][i][2*pr];
      float v1 = p3[0][i][2*pr+1] + p3[1][i][2*pr+1];
      wsu[OFF_V0P + (size_t)(r0+i)*64 + pr] = pkf16(v0, v1);
    }
  }
  __syncthreads();   // qrow ready; p1..p3 free

  // --- C: qs-pack, qe compute, sc, GCN aggregation ---
  if (t < 128) {
    int i = t >> 6, pr = t & 63;
    wsu[OFF_QSP + (size_t)(r0+i)*64 + pr] = pkf16(qrow[i*132 + 2*pr], qrow[i*132 + 2*pr+1]);
  }
  {
    int i = t >> 7, he = t & 127, hh = he >> 5, e = he & 31;
    float acc = 0.f;
    #pragma unroll
    for (int j = 0; j < 32; ++j)
      acc += ws[OFF_WKE + (hh*32 + j)*32 + e] * qrow[i*132 + hh*32 + j];
    qe_l[i*132 + he] = acc;
  }
  if (t < 8) {
    int i = t >> 2, hh = t & 3;
    float acc = 0.f;
    #pragma unroll
    for (int j = 0; j < 32; ++j)
      acc += qrow[i*132 + hh*32 + j] * ws[OFF_KB + hh*32 + j];
    ws[OFF_SC + (size_t)(r0+i)*4 + hh] = acc;
  }
  {
    float ag0=0, ag1=0, dg0=0, dg1=0;
    #pragma unroll 4
    for (int mm = 0; mm < 128; ++mm) {
      int ml = kh*128 + mm;
      float hv = h[((size_t)b*256 + ml)*128 + d];
      float a0 = adj_lds[ml]       + ((ml == n0)     ? 1.0f : 0.0f);
      float a1 = adj_lds[256 + ml] + ((ml == n0 + 1) ? 1.0f : 0.0f);
      ag0 += a0*hv; ag1 += a1*hv; dg0 += a0; dg1 += a1;
    }
    p1[kh][0][d]=ag0; p1[kh][1][d]=ag1;
    if (d == 0) { dpart[kh][0]=dg0; dpart[kh][1]=dg1; }
  }
  __syncthreads();

  // --- D: qe-pack + ha ---
  if (t < 128) {
    int i = t >> 6, pr = t & 63;
    wsu[OFF_QEP + (size_t)(r0+i)*64 + pr] = pkf16(qe_l[i*132 + 2*pr], qe_l[i*132 + 2*pr+1]);
  }
  {
    int i = t >> 7, dd = t & 127;
    ha_lds[i*132 + dd] = (p1[0][i][dd] + p1[1][i][dd]) / (dpart[0][i] + dpart[1][i]);
  }
  __syncthreads();

  // --- E: gcn matvec (transposed, coalesced) ---
  {
    const float* gwT = ws + OFF_GWT;
    float g0=0, g1=0;
    #pragma unroll 4
    for (int kk = 0; kk < 64; ++kk) {
      int k = kh*64 + kk;
      float gw = gwT[k*128+d];
      g0 += gw * ha_lds[k];
      g1 += gw * ha_lds[132 + k];
    }
    p2[kh][0][d]=g0; p2[kh][1][d]=g1;
  }
  __syncthreads();
  {
    int i = t >> 7, dd = t & 127;
    ws[OFF_HG + (size_t)(r0+i)*128 + dd] = p2[0][i][dd] + p2[1][i][dd] + gcn_b[dd];
  }
}

// ---------------------------------------------------------------------------
// Kernel C (attn): R4 skeleton + f16 dot2 + unnormalized-exp softmax.
// One block per (b,n). 4 barriers. Writes normalized ebar/ov to ws.
// ---------------------------------------------------------------------------
__global__ __launch_bounds__(256, 4) void attn_kernel(
    const float* __restrict__ edge, const float* __restrict__ adj,
    const float* __restrict__ srcm, const float* __restrict__ ws,
    float* __restrict__ dummy)
{
  __shared__ unsigned int e_lds[256*18];  // f16-packed edge rows: 16 data + mask + hole
  __shared__ float s_lds[4*264];          // unnormalized exp, stride 264
  __shared__ float part4[8*132];          // ebar partials
  __shared__ float part5[8*132];          // ov partials
  __shared__ float wpart[16];

  const int t  = threadIdx.x;
  const int bn = blockIdx.x;
  const int b  = bn >> 8;
  const int hh = t & 3;
  const int mq = t >> 2;
  const unsigned int* wsu = (const unsigned int*)ws;

  // ---- P1: coalesced edge tile -> f16 LDS; mask -> slot 16 ----
  {
    const float4* et = (const float4*)(edge + (size_t)bn*8192);
    #pragma unroll
    for (int it = 0; it < 8; ++it) {
      int fi = it*256 + t;
      float4 v = et[fi];
      int row = fi >> 3, c4 = fi & 7;
      uint2 pk;
      pk.x = pkf16(v.x, v.y);
      pk.y = pkf16(v.z, v.w);
      *(uint2*)(e_lds + row*18 + c4*2) = pk;
    }
    float mp = adj[(size_t)bn*256 + t] * srcm[(size_t)bn*256 + t];
    e_lds[t*18 + 16] = __float_as_uint(mp);
  }
  // per-lane q / qe packed registers for its head
  unsigned int qs_pk[16], qe_pk[16];
  {
    const uint4* qp = (const uint4*)(wsu + OFF_QSP + (size_t)bn*64 + hh*16);
    const uint4* qe = (const uint4*)(wsu + OFF_QEP + (size_t)bn*64 + hh*16);
    #pragma unroll
    for (int j = 0; j < 4; ++j) {
      uint4 a = qp[j];
      qs_pk[4*j+0]=a.x; qs_pk[4*j+1]=a.y; qs_pk[4*j+2]=a.z; qs_pk[4*j+3]=a.w;
      uint4 c = qe[j];
      qe_pk[4*j+0]=c.x; qe_pk[4*j+1]=c.y; qe_pk[4*j+2]=c.z; qe_pk[4*j+3]=c.w;
    }
  }
  float sconst = ws[OFF_SC + (size_t)bn*4 + hh];
  __syncthreads();

  // ---- P2: scores, 4 passes; unnormalized exp into s_lds ----
  float exacc = 0.f;
  {
    const unsigned int* K0 = wsu + OFF_K0P + (size_t)b*256*64;
    for (int pass = 0; pass < 4; ++pass) {
      int mm = (pass << 6) | mq;
      float acc = sconst;
      const uint4* kr4 = (const uint4*)(K0 + (size_t)mm*64 + hh*16);
      #pragma unroll
      for (int j4 = 0; j4 < 4; ++j4) {
        uint4 kw = kr4[j4];
        acc = fdot2(qs_pk[4*j4+0], kw.x, acc);
        acc = fdot2(qs_pk[4*j4+1], kw.y, acc);
        acc = fdot2(qs_pk[4*j4+2], kw.z, acc);
        acc = fdot2(qs_pk[4*j4+3], kw.w, acc);
      }
      const uint2* er = (const uint2*)(e_lds + mm*18);
      #pragma unroll
      for (int j2 = 0; j2 < 8; ++j2) {
        uint2 w = er[j2];
        acc = fdot2(qe_pk[2*j2+0], w.x, acc);
        acc = fdot2(qe_pk[2*j2+1], w.y, acc);
      }
      float mp = __uint_as_float(e_lds[mm*18 + 16]);
      float ex = (mp == 0.0f) ? 0.0f : __expf(acc);   // no max-sub: |s| << 88
      s_lds[hh*264 + mm] = ex;
      exacc += ex;
    }
    // reduce exp-sums across lanes with same head
    exacc += __shfl_down(exacc, 4);
    exacc += __shfl_down(exacc, 8);
    exacc += __shfl_down(exacc, 16);
    exacc += __shfl_down(exacc, 32);
    if ((t & 63) < 4) wpart[(t >> 6)*4 + hh] = exacc;
  }
  __syncthreads();

  // ---- P3: ebar / ov partials in one m-sweep (unnormalized) ----
  {
    int ms  = t >> 5;
    int hh4 = (t >> 3) & 3, e4 = t & 7;
    int c   = t & 31,  hh5 = c >> 3;
    float p4x=0,p4y=0,p4z=0,p4w=0;
    float p5x=0,p5y=0,p5z=0,p5w=0;
    const unsigned int* vrow = wsu + OFF_V0P + (size_t)b*256*64;
    for (int jm = 0; jm < 32; ++jm) {
      int mm = ms*32 + jm;
      float a4 = s_lds[hh4*264 + mm];
      uint2 w = *(const uint2*)(e_lds + mm*18 + e4*2);
      half2_t e0 = u2h(w.x), e1 = u2h(w.y);
      p4x += a4*(float)e0.x; p4y += a4*(float)e0.y;
      p4z += a4*(float)e1.x; p4w += a4*(float)e1.y;
      float a5 = s_lds[hh5*264 + mm];
      uint2 vv = *(const uint2*)(vrow + (size_t)mm*64 + c*2);
      half2_t v0 = u2h(vv.x), v1 = u2h(vv.y);
      p5x += a5*(float)v0.x; p5y += a5*(float)v0.y;
      p5z += a5*(float)v1.x; p5w += a5*(float)v1.y;
    }
    float4 f4; f4.x=p4x; f4.y=p4y; f4.z=p4z; f4.w=p4w;
    *(float4*)(part4 + ms*132 + hh4*32 + e4*4) = f4;
    float4 f5; f5.x=p5x; f5.y=p5y; f5.z=p5z; f5.w=p5w;
    *(float4*)(part5 + ms*132 + c*4) = f5;
  }
  __syncthreads();

  // ---- P4: reduce partials, normalize, write ebar/ov ----
  if (t < 128) {
    int ht = t >> 5;
    float inv = 1.0f / (wpart[ht] + wpart[4+ht] + wpart[8+ht] + wpart[12+ht]);
    float se = 0.f, s2 = 0.f;
    #pragma unroll
    for (int g = 0; g < 8; ++g) { se += part4[g*132 + t]; s2 += part5[g*132 + t]; }
    float* wso = (float*)ws;
    wso[OFF_EB + (size_t)bn*128 + t] = se * inv;
    wso[OFF_OV + (size_t)bn*128 + t] = s2 * inv;
  }
  (void)dummy;
}

// ---------------------------------------------------------------------------
// Kernel D (epi): o = ov + WveT@ebar + vb; x = h + o@out_w^T + out_b;
// LN(x) + HG -> out. 4 rows/block, grid 512.
// ---------------------------------------------------------------------------
__global__ __launch_bounds__(256) void epi_kernel(
    const float* __restrict__ h, const float* __restrict__ out_b,
    const float* __restrict__ ln_g, const float* __restrict__ ln_b,
    const float* __restrict__ ws, float* __restrict__ out)
{
  __shared__ float eb_l[4*132];
  __shared__ float o_l[4*132];
  __shared__ float xl[4*132];
  __shared__ float pp[2][4][128];
  __shared__ float stat[8];

  int t = threadIdx.x;
  int d = t & 127, kh = t >> 7;
  int r0 = blockIdx.x * 4;

  #pragma unroll
  for (int rep = 0; rep < 2; ++rep) {
    int idx = rep*256 + t, i = idx >> 7, dd = idx & 127;
    eb_l[i*132 + dd] = ws[OFF_EB + (size_t)(r0+i)*128 + dd];
  }
  __syncthreads();

  #pragma unroll
  for (int rep = 0; rep < 2; ++rep) {
    int idx = rep*256 + t, i = idx >> 7, dd = idx & 127;
    int hd = dd >> 5;
    float acc = ws[OFF_OV + (size_t)(r0+i)*128 + dd] + ws[OFF_VB + dd];
    const float* wveT = ws + OFF_WVET;
    #pragma unroll 4
    for (int e = 0; e < 32; ++e) acc += wveT[e*128 + dd] * eb_l[i*132 + hd*32 + e];
    o_l[i*132 + dd] = acc;
  }
  __syncthreads();

  {
    const float* owT = ws + OFF_OWT;
    float xa[4] = {0,0,0,0};
    #pragma unroll 4
    for (int kk = 0; kk < 64; ++kk) {
      int k = kh*64 + kk;
      float ow = owT[k*128 + d];
      #pragma unroll
      for (int i = 0; i < 4; ++i) xa[i] += ow * o_l[i*132 + k];
    }
    #pragma unroll
    for (int i = 0; i < 4; ++i) pp[kh][i][d] = xa[i];
  }
  __syncthreads();

  #pragma unroll
  for (int rep = 0; rep < 2; ++rep) {
    int idx = rep*256 + t, i = idx >> 7, dd = idx & 127;
    xl[i*132 + dd] = pp[0][i][dd] + pp[1][i][dd] + out_b[dd]
                   + h[(size_t)(r0+i)*128 + dd];
  }
  __syncthreads();

  {
    int i = t >> 6, l = t & 63;
    float x0 = xl[i*132 + l], x1 = xl[i*132 + l + 64];
    float s = x0 + x1, ss = x0*x0 + x1*x1;
    #pragma unroll
    for (int off = 32; off > 0; off >>= 1) {
      s  += __shfl_down(s,  off);
      ss += __shfl_down(ss, off);
    }
    if (l == 0) {
      float mu  = s * (1.0f/128.0f);
      float var = ss * (1.0f/128.0f) - mu*mu;
      stat[i]   = mu;
      stat[4+i] = rsqrtf(var + 1e-5f);
    }
  }
  __syncthreads();

  #pragma unroll
  for (int rep = 0; rep < 2; ++rep) {
    int idx = rep*256 + t, i = idx >> 7, dd = idx & 127;
    float x = xl[i*132 + dd];
    out[(size_t)(r0+i)*128 + dd] =
        ln_g[dd]*(x - stat[i])*stat[4+i] + ln_b[dd] + ws[OFF_HG + (size_t)(r0+i)*128 + dd];
  }
}

// ---------------------------------------------------------------------------
extern "C" void kernel_launch(void* const* d_in, const int* in_sizes, int n_in,
                              void* d_out, int out_size, void* d_ws, size_t ws_size,
                              hipStream_t stream) {
  (void)in_sizes; (void)n_in; (void)out_size; (void)ws_size;
  const float* h     = (const float*)d_in[0];
  const float* adj   = (const float*)d_in[1];
  const float* edge  = (const float*)d_in[2];
  const float* srcm  = (const float*)d_in[3];
  const float* gcn_w = (const float*)d_in[4];
  const float* gcn_b = (const float*)d_in[5];
  const float* edge_w= (const float*)d_in[6];
  const float* edge_b= (const float*)d_in[7];
  const float* wq    = (const float*)d_in[8];
  const float* wk    = (const float*)d_in[9];
  const float* wv    = (const float*)d_in[10];
  const float* bq    = (const float*)d_in[11];
  const float* bk    = (const float*)d_in[12];
  const float* bv    = (const float*)d_in[13];
  const float* out_w = (const float*)d_in[14];
  const float* out_b = (const float*)d_in[15];
  const float* ln_g  = (const float*)d_in[16];
  const float* ln_b  = (const float*)d_in[17];

  float* ws  = (float*)d_ws;   // needs >= 5.64 MB
  float* out = (float*)d_out;

  prep_kernel<<<353, 256, 0, stream>>>(wq, wk, wv, out_w, gcn_w, edge_w, edge_b, bk, bv, ws);
  proj_kernel<<<1024, 256, 0, stream>>>(h, adj, bq, gcn_b, ws);
  attn_kernel<<<2048, 256, 0, stream>>>(edge, adj, srcm, ws, out);
  epi_kernel<<<512, 256, 0, stream>>>(h, out_b, ln_g, ln_b, ws, out);
}